// Round 8
// baseline (896.717 us; speedup 1.0000x reference)
//
#include <hip/hip_runtime.h>
#include <math.h>

#define N_NODES 65536
#define N_EDGES 524288
#define IN_CH 128
#define FHC 256
#define NCLS 3
#define NPG 32
#define NGRAPH (N_NODES / NPG)

typedef __attribute__((ext_vector_type(8))) short bfrag;   // 8 bf16 = 4 VGPR (MFMA A/B)
typedef __attribute__((ext_vector_type(4))) float facc;    // 4 f32 (MFMA C/D)

__device__ inline float sigmoidf_(float x) { return 1.0f / (1.0f + expf(-x)); }

// branch-free fast gates: v_exp_f32 + v_rcp_f32; saturate correctly at +-inf
__device__ __forceinline__ float fast_sigmoid(float x) {
    return __builtin_amdgcn_rcpf(1.0f + __expf(-x));
}
__device__ __forceinline__ float fast_tanh(float x) {
    return 1.0f - 2.0f * __builtin_amdgcn_rcpf(__expf(2.0f * x) + 1.0f);
}

__device__ inline short f2bf(float f) {  // RNE float->bf16 bits
    union { float f; unsigned u; } v; v.f = f;
    unsigned r = v.u + 0x7fffu + ((v.u >> 16) & 1u);
    return (short)(r >> 16);
}
__device__ inline float bf2f(short s) {
    union { unsigned u; float f; } v; v.u = ((unsigned)(unsigned short)s) << 16;
    return v.f;
}

// async global->LDS, 16B per lane; LDS dest = wave-uniform base + lane*16 (HW)
__device__ __forceinline__ void gld16(const short* g, short* l) {
    __builtin_amdgcn_global_load_lds(
        (const __attribute__((address_space(1))) void*)g,
        (__attribute__((address_space(3))) void*)l, 16, 0, 0);
}

// ---------------- weight convert: gg_w -> transposed bf16, w_ih/w_hh -> bf16 ----------------
__global__ void convert_kernel(const float* __restrict__ gg_w, const float* __restrict__ wih,
                               const float* __restrict__ whh, short* __restrict__ ggT,
                               short* __restrict__ wih16, short* __restrict__ whh16) {
    int t = blockIdx.x * 256 + threadIdx.x;  // 0 .. 8*FHC*FHC-1
    if (t < 2 * FHC * FHC) {
        int i = t >> 16, r = t & 65535, n = r >> 8, k = r & 255;
        ggT[t] = f2bf(gg_w[i * FHC * FHC + k * FHC + n]);  // out [i][n][k]
    } else if (t < 2 * FHC * FHC + 3 * FHC * FHC) {
        int u = t - 2 * FHC * FHC;
        wih16[u] = f2bf(wih[u]);
    } else {
        int u = t - 5 * FHC * FHC;
        whh16[u] = f2bf(whh[u]);
    }
}

// ---------------- pad x [N,128] fp32 -> h [N,256] bf16 ----------------
__global__ void pad16_kernel(const float* __restrict__ x, short* __restrict__ h) {
    int idx = blockIdx.x * 256 + threadIdx.x;  // short4 granularity over N*64
    int c4 = idx & 63, n = idx >> 6;
    short4 v = {0, 0, 0, 0};
    if (c4 < 32) {
        float4 xv = reinterpret_cast<const float4*>(x)[n * 32 + c4];
        v.x = f2bf(xv.x); v.y = f2bf(xv.y); v.z = f2bf(xv.z); v.w = f2bf(xv.w);
    }
    reinterpret_cast<short4*>(h)[idx] = v;
}

// ================= CSR build =================
__global__ void hist_kernel(const int* __restrict__ ei, int* __restrict__ deg) {
    int e = blockIdx.x * 256 + threadIdx.x;
    atomicAdd(&deg[ei[N_EDGES + e]], 1);
}

__global__ void scan_reduce_kernel(const int* __restrict__ deg, int* __restrict__ bsum) {
    __shared__ int s[256];
    int t = threadIdx.x;
    s[t] = deg[blockIdx.x * 256 + t];
    __syncthreads();
    for (int off = 128; off > 0; off >>= 1) {
        if (t < off) s[t] += s[t + off];
        __syncthreads();
    }
    if (t == 0) bsum[blockIdx.x] = s[0];
}

__global__ void scan_bsum_kernel(const int* __restrict__ bsum, int* __restrict__ boff) {
    __shared__ int s[256];
    int t = threadIdx.x;
    int v = bsum[t];
    s[t] = v;
    __syncthreads();
    for (int off = 1; off < 256; off <<= 1) {
        int u = (t >= off) ? s[t - off] : 0;
        __syncthreads();
        s[t] += u;
        __syncthreads();
    }
    boff[t] = s[t] - v;  // exclusive
}

__global__ void scan_write_kernel(const int* __restrict__ deg, const int* __restrict__ boff,
                                  int* __restrict__ rowptr, int* __restrict__ cur) {
    __shared__ int s[256];
    int t = threadIdx.x, gid = blockIdx.x * 256 + t;
    int v = deg[gid];
    s[t] = v;
    __syncthreads();
    for (int off = 1; off < 256; off <<= 1) {
        int u = (t >= off) ? s[t - off] : 0;
        __syncthreads();
        s[t] += u;
        __syncthreads();
    }
    int excl = boff[blockIdx.x] + s[t] - v;
    rowptr[gid] = excl;
    cur[gid] = excl;
    if (gid == N_NODES - 1) rowptr[N_NODES] = excl + v;
}

__global__ void fill_kernel(const int* __restrict__ ei, const float* __restrict__ ea,
                            int* __restrict__ cur, int2* __restrict__ csr) {
    int e = blockIdx.x * 256 + threadIdx.x;
    int dst = ei[N_EDGES + e];
    int pos = atomicAdd(&cur[dst], 1);
    csr[pos] = make_int2(ei[e], __float_as_int(ea[e]));
}

// ---------------- gather: agg16[n] = sum_{e: dst=n} m16[src_e] * w_e ----------------
__global__ __launch_bounds__(256) void gather_kernel(const short* __restrict__ m,
                                                     const int* __restrict__ rowptr,
                                                     const int2* __restrict__ csr,
                                                     short* __restrict__ agg16) {
    int node = blockIdx.x * 4 + (threadIdx.x >> 6);
    int lane = threadIdx.x & 63;
    int beg = rowptr[node], end = rowptr[node + 1];
    float a0 = 0.f, a1 = 0.f, a2 = 0.f, a3 = 0.f;
    for (int j = beg; j < end; ++j) {
        int2 e = csr[j];
        float w = __int_as_float(e.y);
        short4 v = reinterpret_cast<const short4*>(m)[(size_t)e.x * 64 + lane];
        a0 += bf2f(v.x) * w;
        a1 += bf2f(v.y) * w;
        a2 += bf2f(v.z) * w;
        a3 += bf2f(v.w) * w;
    }
    short4 o;
    o.x = f2bf(a0); o.y = f2bf(a1); o.z = f2bf(a2); o.w = f2bf(a3);
    reinterpret_cast<short4*>(agg16)[(size_t)node * 64 + lane] = o;
}

// ---------------- m16 = h16 @ ggT^T : 128x128 tile, global_load_lds + XOR-swizzled LDS ----
__global__ __launch_bounds__(256, 2) void mgemm_kernel(const short* __restrict__ A,
                                                       const short* __restrict__ W,
                                                       short* __restrict__ C) {
    __shared__ __align__(16) short As[128 * 32];
    __shared__ __align__(16) short Ws[128 * 32];
    int tid = threadIdx.x;
    int lane = tid & 63, wv = tid >> 6, fr = lane & 15, fc = lane >> 4;
    int m0 = blockIdx.x * 128, n0 = blockIdx.y * 128;
    int srow = lane >> 2;                        // staging: row within 16-row chunk
    int scol = (lane & 3) ^ ((lane >> 3) & 3);   // staging: pre-swizzled 16B slot
    const short* gsrc[4];
    short* ldst[4];
#pragma unroll
    for (int i = 0; i < 4; ++i) {
        int ch = wv * 4 + i;
        if (ch < 8) {
            ldst[i] = &As[ch * 512];
            gsrc[i] = A + (size_t)(m0 + ch * 16 + srow) * FHC + scol * 8;
        } else {
            ldst[i] = &Ws[(ch - 8) * 512];
            gsrc[i] = W + (size_t)(n0 + (ch - 8) * 16 + srow) * FHC + scol * 8;
        }
    }
    int fcs = fc ^ ((fr >> 1) & 3);  // read-side swizzled slot
    facc acc[2][8] = {};
    for (int k0 = 0; k0 < FHC; k0 += 32) {
#pragma unroll
        for (int i = 0; i < 4; ++i) gld16(gsrc[i] + k0, ldst[i]);
        __syncthreads();
        int ar = (wv * 32 + fr) * 32 + fcs * 8;
        bfrag a0 = *reinterpret_cast<bfrag*>(&As[ar]);
        bfrag a1 = *reinterpret_cast<bfrag*>(&As[ar + 16 * 32]);
#pragma unroll
        for (int cf = 0; cf < 8; ++cf) {
            bfrag b = *reinterpret_cast<bfrag*>(&Ws[(cf * 16 + fr) * 32 + fcs * 8]);
            acc[0][cf] = __builtin_amdgcn_mfma_f32_16x16x32_bf16(a0, b, acc[0][cf], 0, 0, 0);
            acc[1][cf] = __builtin_amdgcn_mfma_f32_16x16x32_bf16(a1, b, acc[1][cf], 0, 0, 0);
        }
        __syncthreads();
    }
#pragma unroll
    for (int s = 0; s < 2; ++s)
#pragma unroll
        for (int cf = 0; cf < 8; ++cf)
#pragma unroll
            for (int r = 0; r < 4; ++r) {
                int node = m0 + wv * 32 + s * 16 + fc * 4 + r;
                int c = n0 + cf * 16 + fr;
                C[(size_t)node * FHC + c] = f2bf(acc[s][cf][r]);
            }
}

// ---------------- fused GRU: weight-stationary registers + streamed A tiles ----------------
// grid (256, 4); block = 4 waves, 4 blocks/CU. Wave owns 16 gate-cols; 6 mats x K=256
// weight frags live in registers (loaded once). Per 16-row node tile: stage agg+h (16KB,
// dbuf, gld16+swizzle), counted vmcnt(8), 48 barrier-free MFMA, LDS-hold fast-math epilogue.
__global__ __launch_bounds__(256, 4) void gru_mfma_kernel(
    const short* __restrict__ agg16, const short* __restrict__ hin, short* __restrict__ hout,
    const short* __restrict__ wih16, const short* __restrict__ whh16,
    const float* __restrict__ bih, const float* __restrict__ bhh) {
    __shared__ __align__(16) short lds[2 * 16 * 512];  // 2 bufs x (8 agg + 8 h chunks) x 1KB
    int tid = threadIdx.x;
    int lane = tid & 63, wv = tid >> 6, fr = lane & 15, fc = lane >> 4;
    int c = blockIdx.y * 64 + wv * 16 + fr;  // gate column owned by this lane

    // ---- weight registers: 6 mats x 8 ksteps, static-indexed (stay in VGPRs/AGPRs) ----
    bfrag wreg[6][8];
    {
        size_t roff = (size_t)c * FHC + fc * 8;
#pragma unroll
        for (int ks = 0; ks < 8; ++ks) {
            wreg[0][ks] = *reinterpret_cast<const bfrag*>(wih16 + roff + ks * 32);
            wreg[1][ks] = *reinterpret_cast<const bfrag*>(wih16 + (size_t)256 * FHC + roff + ks * 32);
            wreg[2][ks] = *reinterpret_cast<const bfrag*>(wih16 + (size_t)512 * FHC + roff + ks * 32);
            wreg[3][ks] = *reinterpret_cast<const bfrag*>(whh16 + roff + ks * 32);
            wreg[4][ks] = *reinterpret_cast<const bfrag*>(whh16 + (size_t)256 * FHC + roff + ks * 32);
            wreg[5][ks] = *reinterpret_cast<const bfrag*>(whh16 + (size_t)512 * FHC + roff + ks * 32);
        }
    }
    float br = bih[c] + bhh[c];
    float bz = bih[c + 256] + bhh[c + 256];
    float big = bih[c + 512], bhg = bhh[c + 512];

    // ---- staging setup: 16 chunks (8 agg + 8 h), 4 per wave ----
    int srow = lane >> 2;
    int scol = (lane & 3) ^ ((lane >> 3) & 3);
    const short* gb[4];
    int ldsoff[4];
#pragma unroll
    for (int i = 0; i < 4; ++i) {
        int ch = wv * 4 + i;
        int mat = ch >> 3, ks = ch & 7;
        const short* src = mat ? hin : agg16;
        gb[i] = src + (size_t)srow * FHC + ks * 32 + scol * 8;
        ldsoff[i] = ch * 512;
    }
    int fcs = fc ^ ((fr >> 1) & 3);
    int lo = (fr * 4 + fcs) * 8;
    const int NT = 16;
    int tile0 = blockIdx.x * NT;

    // hold = hin[node, c] read from the staged H tile in LDS (inverse write swizzle):
    // chunk 8+(c>>5); within: (row*4 + ((c>>3)&3 ^ ((row>>1)&3)))*8 + (c&7)
    int hbase = (8 + (c >> 5)) * 512 + (c & 7);
    int hg = (c >> 3) & 3;

    auto STAGE = [&](int t, int bufsel) {
        size_t noff = (size_t)(tile0 + t) * 16 * FHC;
        short* dst = &lds[bufsel * 8192];
#pragma unroll
        for (int i = 0; i < 4; ++i) gld16(gb[i] + noff, dst + ldsoff[i]);
    };

    STAGE(0, 0);
    for (int t = 0; t < NT; ++t) {
        int cur = t & 1;
        if (t + 1 < NT) {
            STAGE(t + 1, cur ^ 1);
            // in flight: stores epi(t-1)<=4 + stage(t+1)=4; vmcnt(8) drains stage(t)
            asm volatile("s_waitcnt vmcnt(8)" ::: "memory");
        } else {
            asm volatile("s_waitcnt vmcnt(0)" ::: "memory");
        }
        __builtin_amdgcn_sched_barrier(0);
        __builtin_amdgcn_s_barrier();
        const short* B = &lds[cur * 8192];
        facc aR = {}, aZ = {}, aG = {}, aH = {};
#pragma unroll
        for (int ks = 0; ks < 8; ++ks) {
            bfrag ag = *reinterpret_cast<const bfrag*>(B + ks * 512 + lo);
            bfrag hh = *reinterpret_cast<const bfrag*>(B + (8 + ks) * 512 + lo);
            aR = __builtin_amdgcn_mfma_f32_16x16x32_bf16(ag, wreg[0][ks], aR, 0, 0, 0);
            aR = __builtin_amdgcn_mfma_f32_16x16x32_bf16(hh, wreg[3][ks], aR, 0, 0, 0);
            aZ = __builtin_amdgcn_mfma_f32_16x16x32_bf16(ag, wreg[1][ks], aZ, 0, 0, 0);
            aZ = __builtin_amdgcn_mfma_f32_16x16x32_bf16(hh, wreg[4][ks], aZ, 0, 0, 0);
            aG = __builtin_amdgcn_mfma_f32_16x16x32_bf16(ag, wreg[2][ks], aG, 0, 0, 0);
            aH = __builtin_amdgcn_mfma_f32_16x16x32_bf16(hh, wreg[5][ks], aH, 0, 0, 0);
        }
        int node0 = (tile0 + t) * 16;
#pragma unroll
        for (int r = 0; r < 4; ++r) {
            int row = fc * 4 + r;
            float hold = bf2f(B[hbase + (row * 4 + (hg ^ ((row >> 1) & 3))) * 8]);
            float rg = fast_sigmoid(aR[r] + br);
            float z = fast_sigmoid(aZ[r] + bz);
            float g = fast_tanh(aG[r] + big + rg * (aH[r] + bhg));
            hout[(size_t)(node0 + row) * FHC + c] = f2bf(g + z * (hold - g));
        }
        __builtin_amdgcn_s_barrier();  // buf[cur] fully consumed before stage(t+2) overwrites
    }
}

// ---------------- conv1d(k=1) head: y1[n] = relu(sum_f relu(h[n,f])*w[f] + b) ----------------
__global__ void cnn_kernel(const short* __restrict__ h, const float* __restrict__ w,
                           const float* __restrict__ b, float* __restrict__ y1) {
    int node = blockIdx.x * 4 + (threadIdx.x >> 6);
    int lane = threadIdx.x & 63;
    short4 hv = reinterpret_cast<const short4*>(h)[(size_t)node * 64 + lane];
    float4 wv = reinterpret_cast<const float4*>(w)[lane];
    float p = fmaxf(bf2f(hv.x), 0.f) * wv.x + fmaxf(bf2f(hv.y), 0.f) * wv.y +
              fmaxf(bf2f(hv.z), 0.f) * wv.z + fmaxf(bf2f(hv.w), 0.f) * wv.w;
#pragma unroll
    for (int off = 32; off > 0; off >>= 1) p += __shfl_down(p, off, 64);
    if (lane == 0) y1[node] = fmaxf(p + b[0], 0.f);
}

// ---------------- per-graph MLP + softmax ----------------
__global__ __launch_bounds__(256) void head_kernel(
    const float* __restrict__ y1, const float* __restrict__ l1w,
    const float* __restrict__ l1b, const float* __restrict__ l2w,
    const float* __restrict__ l2b, float* __restrict__ out) {
    __shared__ float ys[32];
    __shared__ float zs[256];
    __shared__ float os[3];
    int b = blockIdx.x, tid = threadIdx.x;
    if (tid < 32) ys[tid] = y1[b * 32 + tid];
    __syncthreads();
    float acc = l1b[tid];
#pragma unroll
    for (int k = 0; k < 32; ++k) acc += ys[k] * l1w[tid * 32 + k];
    zs[tid] = fmaxf(acc, 0.f);
    __syncthreads();
    int wave = tid >> 6, lane = tid & 63;
    if (wave < 3) {
        float p = 0.f;
#pragma unroll
        for (int j = 0; j < 4; ++j) p += zs[lane + j * 64] * l2w[wave * 256 + lane + j * 64];
#pragma unroll
        for (int off = 32; off > 0; off >>= 1) p += __shfl_down(p, off, 64);
        if (lane == 0) os[wave] = p + l2b[wave];
    }
    __syncthreads();
    if (tid == 0) {
        float mx = fmaxf(os[0], fmaxf(os[1], os[2]));
        float e0 = expf(os[0] - mx), e1 = expf(os[1] - mx), e2 = expf(os[2] - mx);
        float s = e0 + e1 + e2;
        out[b * 3 + 0] = e0 / s;
        out[b * 3 + 1] = e1 / s;
        out[b * 3 + 2] = e2 / s;
    }
}

extern "C" void kernel_launch(void* const* d_in, const int* in_sizes, int n_in,
                              void* d_out, int out_size, void* d_ws, size_t ws_size,
                              hipStream_t stream) {
    const float* x = (const float*)d_in[0];
    const int* ei = (const int*)d_in[1];
    const float* ea = (const float*)d_in[2];
    const float* gg_w = (const float*)d_in[3];
    const float* w_ih = (const float*)d_in[4];
    const float* w_hh = (const float*)d_in[5];
    const float* b_ih = (const float*)d_in[6];
    const float* b_hh = (const float*)d_in[7];
    const float* cnn_w = (const float*)d_in[8];
    const float* cnn_b = (const float*)d_in[9];
    const float* l1w = (const float*)d_in[10];
    const float* l1b = (const float*)d_in[11];
    const float* l2w = (const float*)d_in[12];
    const float* l2b = (const float*)d_in[13];
    float* out = (float*)d_out;

    const size_t nodeE = (size_t)N_NODES * FHC;
    char* p = (char*)d_ws;
    short* hA = (short*)p;      p += nodeE * 2;
    short* hB = (short*)p;      p += nodeE * 2;
    short* m16 = (short*)p;     p += nodeE * 2;
    short* agg16 = (short*)p;   p += nodeE * 2;
    short* ggT = (short*)p;     p += (size_t)2 * FHC * FHC * 2;
    short* wih16 = (short*)p;   p += (size_t)3 * FHC * FHC * 2;
    short* whh16 = (short*)p;   p += (size_t)3 * FHC * FHC * 2;
    float* y1 = (float*)p;      p += (size_t)N_NODES * 4;
    int* deg = (int*)p;         p += (size_t)N_NODES * 4;
    int* rowptr = (int*)p;      p += (size_t)(N_NODES + 4) * 4;
    int* cur = (int*)p;         p += (size_t)N_NODES * 4;
    int* bsum = (int*)p;        p += 256 * 4;
    int* boff = (int*)p;        p += 256 * 4;
    int2* csr = (int2*)p;       p += (size_t)N_EDGES * 8;

    dim3 grid_gemm(N_NODES / 128, FHC / 128);
    dim3 grid_gru(256, 4);

    // weights + input prep
    convert_kernel<<<8 * FHC * FHC / 256, 256, 0, stream>>>(gg_w, w_ih, w_hh, ggT, wih16, whh16);
    pad16_kernel<<<N_NODES * 64 / 256, 256, 0, stream>>>(x, hA);

    // CSR build (per call; graph is a fixed input)
    hipMemsetAsync(deg, 0, (size_t)N_NODES * 4, stream);
    hist_kernel<<<N_EDGES / 256, 256, 0, stream>>>(ei, deg);
    scan_reduce_kernel<<<N_NODES / 256, 256, 0, stream>>>(deg, bsum);
    scan_bsum_kernel<<<1, 256, 0, stream>>>(bsum, boff);
    scan_write_kernel<<<N_NODES / 256, 256, 0, stream>>>(deg, boff, rowptr, cur);
    fill_kernel<<<N_EDGES / 256, 256, 0, stream>>>(ei, ea, cur, csr);

    // layer 0: hA -> m16 -> agg16 -> hB
    mgemm_kernel<<<grid_gemm, 256, 0, stream>>>(hA, ggT, m16);
    gather_kernel<<<N_NODES / 4, 256, 0, stream>>>(m16, rowptr, csr, agg16);
    gru_mfma_kernel<<<grid_gru, 256, 0, stream>>>(agg16, hA, hB, wih16, whh16, b_ih, b_hh);

    // layer 1: hB -> m16 -> agg16 -> hA
    mgemm_kernel<<<grid_gemm, 256, 0, stream>>>(hB, ggT + FHC * FHC, m16);
    gather_kernel<<<N_NODES / 4, 256, 0, stream>>>(m16, rowptr, csr, agg16);
    gru_mfma_kernel<<<grid_gru, 256, 0, stream>>>(agg16, hB, hA, wih16, whh16, b_ih, b_hh);

    cnn_kernel<<<N_NODES / 4, 256, 0, stream>>>(hA, cnn_w, cnn_b, y1);
    head_kernel<<<NGRAPH, 256, 0, stream>>>(y1, l1w, l1b, l2w, l2b, out);
}

// Round 9
// 361.342 us; speedup vs baseline: 2.4816x; 2.4816x over previous
//
#include <hip/hip_runtime.h>
#include <math.h>

#define N_NODES 65536
#define N_EDGES 524288
#define IN_CH 128
#define FHC 256
#define NCLS 3
#define NPG 32
#define NGRAPH (N_NODES / NPG)

typedef __attribute__((ext_vector_type(8))) short bfrag;   // 8 bf16 = 4 VGPR (MFMA A/B)
typedef __attribute__((ext_vector_type(4))) float facc;    // 4 f32 (MFMA C/D)

__device__ inline float sigmoidf_(float x) { return 1.0f / (1.0f + expf(-x)); }

// branch-free fast gates: v_exp_f32 + v_rcp_f32; saturate correctly at +-inf
__device__ __forceinline__ float fast_sigmoid(float x) {
    return __builtin_amdgcn_rcpf(1.0f + __expf(-x));
}
__device__ __forceinline__ float fast_tanh(float x) {
    return 1.0f - 2.0f * __builtin_amdgcn_rcpf(__expf(2.0f * x) + 1.0f);
}

__device__ inline short f2bf(float f) {  // RNE float->bf16 bits
    union { float f; unsigned u; } v; v.f = f;
    unsigned r = v.u + 0x7fffu + ((v.u >> 16) & 1u);
    return (short)(r >> 16);
}
__device__ inline float bf2f(short s) {
    union { unsigned u; float f; } v; v.u = ((unsigned)(unsigned short)s) << 16;
    return v.f;
}

// async global->LDS, 16B per lane; LDS dest = wave-uniform base + lane*16 (HW)
__device__ __forceinline__ void gld16(const short* g, short* l) {
    __builtin_amdgcn_global_load_lds(
        (const __attribute__((address_space(1))) void*)g,
        (__attribute__((address_space(3))) void*)l, 16, 0, 0);
}

// ---------------- weight convert: gg_w -> transposed bf16, w_ih/w_hh -> bf16 ----------------
__global__ void convert_kernel(const float* __restrict__ gg_w, const float* __restrict__ wih,
                               const float* __restrict__ whh, short* __restrict__ ggT,
                               short* __restrict__ wih16, short* __restrict__ whh16) {
    int t = blockIdx.x * 256 + threadIdx.x;  // 0 .. 8*FHC*FHC-1
    if (t < 2 * FHC * FHC) {
        int i = t >> 16, r = t & 65535, n = r >> 8, k = r & 255;
        ggT[t] = f2bf(gg_w[i * FHC * FHC + k * FHC + n]);  // out [i][n][k]
    } else if (t < 2 * FHC * FHC + 3 * FHC * FHC) {
        int u = t - 2 * FHC * FHC;
        wih16[u] = f2bf(wih[u]);
    } else {
        int u = t - 5 * FHC * FHC;
        whh16[u] = f2bf(whh[u]);
    }
}

// ---------------- pad x [N,128] fp32 -> h [N,256] bf16 ----------------
__global__ void pad16_kernel(const float* __restrict__ x, short* __restrict__ h) {
    int idx = blockIdx.x * 256 + threadIdx.x;  // short4 granularity over N*64
    int c4 = idx & 63, n = idx >> 6;
    short4 v = {0, 0, 0, 0};
    if (c4 < 32) {
        float4 xv = reinterpret_cast<const float4*>(x)[n * 32 + c4];
        v.x = f2bf(xv.x); v.y = f2bf(xv.y); v.z = f2bf(xv.z); v.w = f2bf(xv.w);
    }
    reinterpret_cast<short4*>(h)[idx] = v;
}

// ================= CSR build =================
__global__ void hist_kernel(const int* __restrict__ ei, int* __restrict__ deg) {
    int e = blockIdx.x * 256 + threadIdx.x;
    atomicAdd(&deg[ei[N_EDGES + e]], 1);
}

__global__ void scan_reduce_kernel(const int* __restrict__ deg, int* __restrict__ bsum) {
    __shared__ int s[256];
    int t = threadIdx.x;
    s[t] = deg[blockIdx.x * 256 + t];
    __syncthreads();
    for (int off = 128; off > 0; off >>= 1) {
        if (t < off) s[t] += s[t + off];
        __syncthreads();
    }
    if (t == 0) bsum[blockIdx.x] = s[0];
}

__global__ void scan_bsum_kernel(const int* __restrict__ bsum, int* __restrict__ boff) {
    __shared__ int s[256];
    int t = threadIdx.x;
    int v = bsum[t];
    s[t] = v;
    __syncthreads();
    for (int off = 1; off < 256; off <<= 1) {
        int u = (t >= off) ? s[t - off] : 0;
        __syncthreads();
        s[t] += u;
        __syncthreads();
    }
    boff[t] = s[t] - v;  // exclusive
}

__global__ void scan_write_kernel(const int* __restrict__ deg, const int* __restrict__ boff,
                                  int* __restrict__ rowptr, int* __restrict__ cur) {
    __shared__ int s[256];
    int t = threadIdx.x, gid = blockIdx.x * 256 + t;
    int v = deg[gid];
    s[t] = v;
    __syncthreads();
    for (int off = 1; off < 256; off <<= 1) {
        int u = (t >= off) ? s[t - off] : 0;
        __syncthreads();
        s[t] += u;
        __syncthreads();
    }
    int excl = boff[blockIdx.x] + s[t] - v;
    rowptr[gid] = excl;
    cur[gid] = excl;
    if (gid == N_NODES - 1) rowptr[N_NODES] = excl + v;
}

__global__ void fill_kernel(const int* __restrict__ ei, const float* __restrict__ ea,
                            int* __restrict__ cur, int2* __restrict__ csr) {
    int e = blockIdx.x * 256 + threadIdx.x;
    int dst = ei[N_EDGES + e];
    int pos = atomicAdd(&cur[dst], 1);
    csr[pos] = make_int2(ei[e], __float_as_int(ea[e]));
}

// ---------------- gather: agg16[n] = sum_{e: dst=n} m16[src_e] * w_e ----------------
__global__ __launch_bounds__(256) void gather_kernel(const short* __restrict__ m,
                                                     const int* __restrict__ rowptr,
                                                     const int2* __restrict__ csr,
                                                     short* __restrict__ agg16) {
    int node = blockIdx.x * 4 + (threadIdx.x >> 6);
    int lane = threadIdx.x & 63;
    int beg = rowptr[node], end = rowptr[node + 1];
    float a0 = 0.f, a1 = 0.f, a2 = 0.f, a3 = 0.f;
    for (int j = beg; j < end; ++j) {
        int2 e = csr[j];
        float w = __int_as_float(e.y);
        short4 v = reinterpret_cast<const short4*>(m)[(size_t)e.x * 64 + lane];
        a0 += bf2f(v.x) * w;
        a1 += bf2f(v.y) * w;
        a2 += bf2f(v.z) * w;
        a3 += bf2f(v.w) * w;
    }
    short4 o;
    o.x = f2bf(a0); o.y = f2bf(a1); o.z = f2bf(a2); o.w = f2bf(a3);
    reinterpret_cast<short4*>(agg16)[(size_t)node * 64 + lane] = o;
}

// ---------------- m16 = h16 @ ggT^T : 128x128 tile, global_load_lds + XOR-swizzled LDS ----
__global__ __launch_bounds__(256, 2) void mgemm_kernel(const short* __restrict__ A,
                                                       const short* __restrict__ W,
                                                       short* __restrict__ C) {
    __shared__ __align__(16) short As[128 * 32];
    __shared__ __align__(16) short Ws[128 * 32];
    int tid = threadIdx.x;
    int lane = tid & 63, wv = tid >> 6, fr = lane & 15, fc = lane >> 4;
    int m0 = blockIdx.x * 128, n0 = blockIdx.y * 128;
    int srow = lane >> 2;                        // staging: row within 16-row chunk
    int scol = (lane & 3) ^ ((lane >> 3) & 3);   // staging: pre-swizzled 16B slot
    const short* gsrc[4];
    short* ldst[4];
#pragma unroll
    for (int i = 0; i < 4; ++i) {
        int ch = wv * 4 + i;
        if (ch < 8) {
            ldst[i] = &As[ch * 512];
            gsrc[i] = A + (size_t)(m0 + ch * 16 + srow) * FHC + scol * 8;
        } else {
            ldst[i] = &Ws[(ch - 8) * 512];
            gsrc[i] = W + (size_t)(n0 + (ch - 8) * 16 + srow) * FHC + scol * 8;
        }
    }
    int fcs = fc ^ ((fr >> 1) & 3);  // read-side swizzled slot
    facc acc[2][8] = {};
    for (int k0 = 0; k0 < FHC; k0 += 32) {
#pragma unroll
        for (int i = 0; i < 4; ++i) gld16(gsrc[i] + k0, ldst[i]);
        __syncthreads();
        int ar = (wv * 32 + fr) * 32 + fcs * 8;
        bfrag a0 = *reinterpret_cast<bfrag*>(&As[ar]);
        bfrag a1 = *reinterpret_cast<bfrag*>(&As[ar + 16 * 32]);
#pragma unroll
        for (int cf = 0; cf < 8; ++cf) {
            bfrag b = *reinterpret_cast<bfrag*>(&Ws[(cf * 16 + fr) * 32 + fcs * 8]);
            acc[0][cf] = __builtin_amdgcn_mfma_f32_16x16x32_bf16(a0, b, acc[0][cf], 0, 0, 0);
            acc[1][cf] = __builtin_amdgcn_mfma_f32_16x16x32_bf16(a1, b, acc[1][cf], 0, 0, 0);
        }
        __syncthreads();
    }
#pragma unroll
    for (int s = 0; s < 2; ++s)
#pragma unroll
        for (int cf = 0; cf < 8; ++cf)
#pragma unroll
            for (int r = 0; r < 4; ++r) {
                int node = m0 + wv * 32 + s * 16 + fc * 4 + r;
                int c = n0 + cf * 16 + fr;
                C[(size_t)node * FHC + c] = f2bf(acc[s][cf][r]);
            }
}

// ---------------- fused GRU: weight-stationary registers + streamed A tiles ----------------
// grid (128, 4); block = 4 waves, 2 blocks/CU (weight-stationary needs ~200 regs -> AGPRs;
// launch_bounds(256,4) forces spill, measured 1GB scratch traffic in R8). Per 16-row tile:
// stage agg+h (16KB, dbuf, gld16+swizzle), counted vmcnt(8), 48 barrier-free MFMA,
// LDS-hold + fast-math epilogue.
__global__ __launch_bounds__(256, 2) void gru_mfma_kernel(
    const short* __restrict__ agg16, const short* __restrict__ hin, short* __restrict__ hout,
    const short* __restrict__ wih16, const short* __restrict__ whh16,
    const float* __restrict__ bih, const float* __restrict__ bhh) {
    __shared__ __align__(16) short lds[2 * 16 * 512];  // 2 bufs x (8 agg + 8 h chunks) x 1KB
    int tid = threadIdx.x;
    int lane = tid & 63, wv = tid >> 6, fr = lane & 15, fc = lane >> 4;
    int c = blockIdx.y * 64 + wv * 16 + fr;  // gate column owned by this lane

    // ---- weight registers: 6 mats x 8 ksteps, static-indexed (VGPR/AGPR resident) ----
    bfrag wreg[6][8];
    {
        size_t roff = (size_t)c * FHC + fc * 8;
#pragma unroll
        for (int ks = 0; ks < 8; ++ks) {
            wreg[0][ks] = *reinterpret_cast<const bfrag*>(wih16 + roff + ks * 32);
            wreg[1][ks] = *reinterpret_cast<const bfrag*>(wih16 + (size_t)256 * FHC + roff + ks * 32);
            wreg[2][ks] = *reinterpret_cast<const bfrag*>(wih16 + (size_t)512 * FHC + roff + ks * 32);
            wreg[3][ks] = *reinterpret_cast<const bfrag*>(whh16 + roff + ks * 32);
            wreg[4][ks] = *reinterpret_cast<const bfrag*>(whh16 + (size_t)256 * FHC + roff + ks * 32);
            wreg[5][ks] = *reinterpret_cast<const bfrag*>(whh16 + (size_t)512 * FHC + roff + ks * 32);
        }
    }
    float br = bih[c] + bhh[c];
    float bz = bih[c + 256] + bhh[c + 256];
    float big = bih[c + 512], bhg = bhh[c + 512];

    // ---- staging setup: 16 chunks (8 agg + 8 h), 4 per wave ----
    int srow = lane >> 2;
    int scol = (lane & 3) ^ ((lane >> 3) & 3);
    const short* gb[4];
    int ldsoff[4];
#pragma unroll
    for (int i = 0; i < 4; ++i) {
        int ch = wv * 4 + i;
        int mat = ch >> 3, ks = ch & 7;
        const short* src = mat ? hin : agg16;
        gb[i] = src + (size_t)srow * FHC + ks * 32 + scol * 8;
        ldsoff[i] = ch * 512;
    }
    int fcs = fc ^ ((fr >> 1) & 3);
    int lo = (fr * 4 + fcs) * 8;
    const int NT = 32;
    int tile0 = blockIdx.x * NT;

    // hold = hin[node, c] read from the staged H tile in LDS (inverse write swizzle):
    // chunk 8+(c>>5); within: (row*4 + ((c>>3)&3 ^ ((row>>1)&3)))*8 + (c&7)
    int hbase = (8 + (c >> 5)) * 512 + (c & 7);
    int hg = (c >> 3) & 3;

    auto STAGE = [&](int t, int bufsel) {
        size_t noff = (size_t)(tile0 + t) * 16 * FHC;
        short* dst = &lds[bufsel * 8192];
#pragma unroll
        for (int i = 0; i < 4; ++i) gld16(gb[i] + noff, dst + ldsoff[i]);
    };

    STAGE(0, 0);
    for (int t = 0; t < NT; ++t) {
        int cur = t & 1;
        if (t + 1 < NT) {
            STAGE(t + 1, cur ^ 1);
            // in flight: stores epi(t-1)<=4 + stage(t+1)=4; vmcnt(8) drains stage(t)
            asm volatile("s_waitcnt vmcnt(8)" ::: "memory");
        } else {
            asm volatile("s_waitcnt vmcnt(0)" ::: "memory");
        }
        __builtin_amdgcn_sched_barrier(0);
        __builtin_amdgcn_s_barrier();
        const short* B = &lds[cur * 8192];
        facc aR = {}, aZ = {}, aG = {}, aH = {};
#pragma unroll
        for (int ks = 0; ks < 8; ++ks) {
            bfrag ag = *reinterpret_cast<const bfrag*>(B + ks * 512 + lo);
            bfrag hh = *reinterpret_cast<const bfrag*>(B + (8 + ks) * 512 + lo);
            aR = __builtin_amdgcn_mfma_f32_16x16x32_bf16(ag, wreg[0][ks], aR, 0, 0, 0);
            aR = __builtin_amdgcn_mfma_f32_16x16x32_bf16(hh, wreg[3][ks], aR, 0, 0, 0);
            aZ = __builtin_amdgcn_mfma_f32_16x16x32_bf16(ag, wreg[1][ks], aZ, 0, 0, 0);
            aZ = __builtin_amdgcn_mfma_f32_16x16x32_bf16(hh, wreg[4][ks], aZ, 0, 0, 0);
            aG = __builtin_amdgcn_mfma_f32_16x16x32_bf16(ag, wreg[2][ks], aG, 0, 0, 0);
            aH = __builtin_amdgcn_mfma_f32_16x16x32_bf16(hh, wreg[5][ks], aH, 0, 0, 0);
        }
        int node0 = (tile0 + t) * 16;
#pragma unroll
        for (int r = 0; r < 4; ++r) {
            int row = fc * 4 + r;
            float hold = bf2f(B[hbase + (row * 4 + (hg ^ ((row >> 1) & 3))) * 8]);
            float rg = fast_sigmoid(aR[r] + br);
            float z = fast_sigmoid(aZ[r] + bz);
            float g = fast_tanh(aG[r] + big + rg * (aH[r] + bhg));
            hout[(size_t)(node0 + row) * FHC + c] = f2bf(g + z * (hold - g));
        }
        __builtin_amdgcn_s_barrier();  // buf[cur] fully consumed before stage(t+2) overwrites
    }
}

// ---------------- conv1d(k=1) head: y1[n] = relu(sum_f relu(h[n,f])*w[f] + b) ----------------
__global__ void cnn_kernel(const short* __restrict__ h, const float* __restrict__ w,
                           const float* __restrict__ b, float* __restrict__ y1) {
    int node = blockIdx.x * 4 + (threadIdx.x >> 6);
    int lane = threadIdx.x & 63;
    short4 hv = reinterpret_cast<const short4*>(h)[(size_t)node * 64 + lane];
    float4 wv = reinterpret_cast<const float4*>(w)[lane];
    float p = fmaxf(bf2f(hv.x), 0.f) * wv.x + fmaxf(bf2f(hv.y), 0.f) * wv.y +
              fmaxf(bf2f(hv.z), 0.f) * wv.z + fmaxf(bf2f(hv.w), 0.f) * wv.w;
#pragma unroll
    for (int off = 32; off > 0; off >>= 1) p += __shfl_down(p, off, 64);
    if (lane == 0) y1[node] = fmaxf(p + b[0], 0.f);
}

// ---------------- per-graph MLP + softmax ----------------
__global__ __launch_bounds__(256) void head_kernel(
    const float* __restrict__ y1, const float* __restrict__ l1w,
    const float* __restrict__ l1b, const float* __restrict__ l2w,
    const float* __restrict__ l2b, float* __restrict__ out) {
    __shared__ float ys[32];
    __shared__ float zs[256];
    __shared__ float os[3];
    int b = blockIdx.x, tid = threadIdx.x;
    if (tid < 32) ys[tid] = y1[b * 32 + tid];
    __syncthreads();
    float acc = l1b[tid];
#pragma unroll
    for (int k = 0; k < 32; ++k) acc += ys[k] * l1w[tid * 32 + k];
    zs[tid] = fmaxf(acc, 0.f);
    __syncthreads();
    int wave = tid >> 6, lane = tid & 63;
    if (wave < 3) {
        float p = 0.f;
#pragma unroll
        for (int j = 0; j < 4; ++j) p += zs[lane + j * 64] * l2w[wave * 256 + lane + j * 64];
#pragma unroll
        for (int off = 32; off > 0; off >>= 1) p += __shfl_down(p, off, 64);
        if (lane == 0) os[wave] = p + l2b[wave];
    }
    __syncthreads();
    if (tid == 0) {
        float mx = fmaxf(os[0], fmaxf(os[1], os[2]));
        float e0 = expf(os[0] - mx), e1 = expf(os[1] - mx), e2 = expf(os[2] - mx);
        float s = e0 + e1 + e2;
        out[b * 3 + 0] = e0 / s;
        out[b * 3 + 1] = e1 / s;
        out[b * 3 + 2] = e2 / s;
    }
}

extern "C" void kernel_launch(void* const* d_in, const int* in_sizes, int n_in,
                              void* d_out, int out_size, void* d_ws, size_t ws_size,
                              hipStream_t stream) {
    const float* x = (const float*)d_in[0];
    const int* ei = (const int*)d_in[1];
    const float* ea = (const float*)d_in[2];
    const float* gg_w = (const float*)d_in[3];
    const float* w_ih = (const float*)d_in[4];
    const float* w_hh = (const float*)d_in[5];
    const float* b_ih = (const float*)d_in[6];
    const float* b_hh = (const float*)d_in[7];
    const float* cnn_w = (const float*)d_in[8];
    const float* cnn_b = (const float*)d_in[9];
    const float* l1w = (const float*)d_in[10];
    const float* l1b = (const float*)d_in[11];
    const float* l2w = (const float*)d_in[12];
    const float* l2b = (const float*)d_in[13];
    float* out = (float*)d_out;

    const size_t nodeE = (size_t)N_NODES * FHC;
    char* p = (char*)d_ws;
    short* hA = (short*)p;      p += nodeE * 2;
    short* hB = (short*)p;      p += nodeE * 2;
    short* m16 = (short*)p;     p += nodeE * 2;
    short* agg16 = (short*)p;   p += nodeE * 2;
    short* ggT = (short*)p;     p += (size_t)2 * FHC * FHC * 2;
    short* wih16 = (short*)p;   p += (size_t)3 * FHC * FHC * 2;
    short* whh16 = (short*)p;   p += (size_t)3 * FHC * FHC * 2;
    float* y1 = (float*)p;      p += (size_t)N_NODES * 4;
    int* deg = (int*)p;         p += (size_t)N_NODES * 4;
    int* rowptr = (int*)p;      p += (size_t)(N_NODES + 4) * 4;
    int* cur = (int*)p;         p += (size_t)N_NODES * 4;
    int* bsum = (int*)p;        p += 256 * 4;
    int* boff = (int*)p;        p += 256 * 4;
    int2* csr = (int2*)p;       p += (size_t)N_EDGES * 8;

    dim3 grid_gemm(N_NODES / 128, FHC / 128);
    dim3 grid_gru(128, 4);

    // weights + input prep
    convert_kernel<<<8 * FHC * FHC / 256, 256, 0, stream>>>(gg_w, w_ih, w_hh, ggT, wih16, whh16);
    pad16_kernel<<<N_NODES * 64 / 256, 256, 0, stream>>>(x, hA);

    // CSR build (per call; graph is a fixed input)
    hipMemsetAsync(deg, 0, (size_t)N_NODES * 4, stream);
    hist_kernel<<<N_EDGES / 256, 256, 0, stream>>>(ei, deg);
    scan_reduce_kernel<<<N_NODES / 256, 256, 0, stream>>>(deg, bsum);
    scan_bsum_kernel<<<1, 256, 0, stream>>>(bsum, boff);
    scan_write_kernel<<<N_NODES / 256, 256, 0, stream>>>(deg, boff, rowptr, cur);
    fill_kernel<<<N_EDGES / 256, 256, 0, stream>>>(ei, ea, cur, csr);

    // layer 0: hA -> m16 -> agg16 -> hB
    mgemm_kernel<<<grid_gemm, 256, 0, stream>>>(hA, ggT, m16);
    gather_kernel<<<N_NODES / 4, 256, 0, stream>>>(m16, rowptr, csr, agg16);
    gru_mfma_kernel<<<grid_gru, 256, 0, stream>>>(agg16, hA, hB, wih16, whh16, b_ih, b_hh);

    // layer 1: hB -> m16 -> agg16 -> hA
    mgemm_kernel<<<grid_gemm, 256, 0, stream>>>(hB, ggT + FHC * FHC, m16);
    gather_kernel<<<N_NODES / 4, 256, 0, stream>>>(m16, rowptr, csr, agg16);
    gru_mfma_kernel<<<grid_gru, 256, 0, stream>>>(agg16, hB, hA, wih16, whh16, b_ih, b_hh);

    cnn_kernel<<<N_NODES / 4, 256, 0, stream>>>(hA, cnn_w, cnn_b, y1);
    head_kernel<<<NGRAPH, 256, 0, stream>>>(y1, l1w, l1b, l2w, l2b, out);
}

// Round 10
// 316.357 us; speedup vs baseline: 2.8345x; 1.1422x over previous
//
#include <hip/hip_runtime.h>
#include <math.h>

#define N_NODES 65536
#define N_EDGES 524288
#define IN_CH 128
#define FHC 256
#define NCLS 3
#define NPG 32
#define NGRAPH (N_NODES / NPG)

typedef __attribute__((ext_vector_type(8))) short bfrag;   // 8 bf16 = 4 VGPR (MFMA A/B)
typedef __attribute__((ext_vector_type(4))) float facc;    // 4 f32 (MFMA C/D)

__device__ inline float sigmoidf_(float x) { return 1.0f / (1.0f + expf(-x)); }

// branch-free fast gates: v_exp_f32 + v_rcp_f32; saturate correctly at +-inf
__device__ __forceinline__ float fast_sigmoid(float x) {
    return __builtin_amdgcn_rcpf(1.0f + __expf(-x));
}
__device__ __forceinline__ float fast_tanh(float x) {
    return 1.0f - 2.0f * __builtin_amdgcn_rcpf(__expf(2.0f * x) + 1.0f);
}

__device__ inline short f2bf(float f) {  // RNE float->bf16 bits
    union { float f; unsigned u; } v; v.f = f;
    unsigned r = v.u + 0x7fffu + ((v.u >> 16) & 1u);
    return (short)(r >> 16);
}
__device__ inline float bf2f(short s) {
    union { unsigned u; float f; } v; v.u = ((unsigned)(unsigned short)s) << 16;
    return v.f;
}

// async global->LDS, 16B per lane; LDS dest = wave-uniform base + lane*16 (HW)
__device__ __forceinline__ void gld16(const short* g, short* l) {
    __builtin_amdgcn_global_load_lds(
        (const __attribute__((address_space(1))) void*)g,
        (__attribute__((address_space(3))) void*)l, 16, 0, 0);
}

// ---------------- weight convert: gg_w -> transposed bf16, w_ih/w_hh -> bf16 ----------------
__global__ void convert_kernel(const float* __restrict__ gg_w, const float* __restrict__ wih,
                               const float* __restrict__ whh, short* __restrict__ ggT,
                               short* __restrict__ wih16, short* __restrict__ whh16) {
    int t = blockIdx.x * 256 + threadIdx.x;  // 0 .. 8*FHC*FHC-1
    if (t < 2 * FHC * FHC) {
        int i = t >> 16, r = t & 65535, n = r >> 8, k = r & 255;
        ggT[t] = f2bf(gg_w[i * FHC * FHC + k * FHC + n]);  // out [i][n][k]
    } else if (t < 2 * FHC * FHC + 3 * FHC * FHC) {
        int u = t - 2 * FHC * FHC;
        wih16[u] = f2bf(wih[u]);
    } else {
        int u = t - 5 * FHC * FHC;
        whh16[u] = f2bf(whh[u]);
    }
}

// ---------------- pad x [N,128] fp32 -> h [N,256] bf16 ----------------
__global__ void pad16_kernel(const float* __restrict__ x, short* __restrict__ h) {
    int idx = blockIdx.x * 256 + threadIdx.x;  // short4 granularity over N*64
    int c4 = idx & 63, n = idx >> 6;
    short4 v = {0, 0, 0, 0};
    if (c4 < 32) {
        float4 xv = reinterpret_cast<const float4*>(x)[n * 32 + c4];
        v.x = f2bf(xv.x); v.y = f2bf(xv.y); v.z = f2bf(xv.z); v.w = f2bf(xv.w);
    }
    reinterpret_cast<short4*>(h)[idx] = v;
}

// ================= CSR build =================
__global__ void hist_kernel(const int* __restrict__ ei, int* __restrict__ deg) {
    int e = blockIdx.x * 256 + threadIdx.x;
    atomicAdd(&deg[ei[N_EDGES + e]], 1);
}

__global__ void scan_reduce_kernel(const int* __restrict__ deg, int* __restrict__ bsum) {
    __shared__ int s[256];
    int t = threadIdx.x;
    s[t] = deg[blockIdx.x * 256 + t];
    __syncthreads();
    for (int off = 128; off > 0; off >>= 1) {
        if (t < off) s[t] += s[t + off];
        __syncthreads();
    }
    if (t == 0) bsum[blockIdx.x] = s[0];
}

__global__ void scan_bsum_kernel(const int* __restrict__ bsum, int* __restrict__ boff) {
    __shared__ int s[256];
    int t = threadIdx.x;
    int v = bsum[t];
    s[t] = v;
    __syncthreads();
    for (int off = 1; off < 256; off <<= 1) {
        int u = (t >= off) ? s[t - off] : 0;
        __syncthreads();
        s[t] += u;
        __syncthreads();
    }
    boff[t] = s[t] - v;  // exclusive
}

__global__ void scan_write_kernel(const int* __restrict__ deg, const int* __restrict__ boff,
                                  int* __restrict__ rowptr, int* __restrict__ cur) {
    __shared__ int s[256];
    int t = threadIdx.x, gid = blockIdx.x * 256 + t;
    int v = deg[gid];
    s[t] = v;
    __syncthreads();
    for (int off = 1; off < 256; off <<= 1) {
        int u = (t >= off) ? s[t - off] : 0;
        __syncthreads();
        s[t] += u;
        __syncthreads();
    }
    int excl = boff[blockIdx.x] + s[t] - v;
    rowptr[gid] = excl;
    cur[gid] = excl;
    if (gid == N_NODES - 1) rowptr[N_NODES] = excl + v;
}

__global__ void fill_kernel(const int* __restrict__ ei, const float* __restrict__ ea,
                            int* __restrict__ cur, int2* __restrict__ csr) {
    int e = blockIdx.x * 256 + threadIdx.x;
    int dst = ei[N_EDGES + e];
    int pos = atomicAdd(&cur[dst], 1);
    csr[pos] = make_int2(ei[e], __float_as_int(ea[e]));
}

// ---------------- gather: agg16[n] = sum_{e: dst=n} m16[src_e] * w_e ----------------
// latency fix: batch-load 8 contiguous csr records, then 8 independent row-gathers
// (one vmcnt group) instead of a serial csr->row chain per edge.
__global__ __launch_bounds__(256) void gather_kernel(const short* __restrict__ m,
                                                     const int* __restrict__ rowptr,
                                                     const int2* __restrict__ csr,
                                                     short* __restrict__ agg16) {
    int node = blockIdx.x * 4 + (threadIdx.x >> 6);
    int lane = threadIdx.x & 63;
    int beg = rowptr[node], end = rowptr[node + 1];
    const short4* m4 = reinterpret_cast<const short4*>(m);
    float a0 = 0.f, a1 = 0.f, a2 = 0.f, a3 = 0.f;
#define GSTEP(E)                                            \
    {                                                       \
        float w = __int_as_float((E).y);                    \
        short4 v = m4[(size_t)(E).x * 64 + lane];           \
        a0 += bf2f(v.x) * w;                                \
        a1 += bf2f(v.y) * w;                                \
        a2 += bf2f(v.z) * w;                                \
        a3 += bf2f(v.w) * w;                                \
    }
    int j = beg;
    for (; j + 8 <= end; j += 8) {
        int2 e0 = csr[j + 0], e1 = csr[j + 1], e2 = csr[j + 2], e3 = csr[j + 3];
        int2 e4 = csr[j + 4], e5 = csr[j + 5], e6 = csr[j + 6], e7 = csr[j + 7];
        GSTEP(e0) GSTEP(e1) GSTEP(e2) GSTEP(e3)
        GSTEP(e4) GSTEP(e5) GSTEP(e6) GSTEP(e7)
    }
    for (; j + 2 <= end; j += 2) {
        int2 e0 = csr[j + 0], e1 = csr[j + 1];
        GSTEP(e0) GSTEP(e1)
    }
    if (j < end) {
        int2 e0 = csr[j];
        GSTEP(e0)
    }
#undef GSTEP
    short4 o;
    o.x = f2bf(a0); o.y = f2bf(a1); o.z = f2bf(a2); o.w = f2bf(a3);
    reinterpret_cast<short4*>(agg16)[(size_t)node * 64 + lane] = o;
}

// ---------------- m16 = h16 @ ggT^T : 128x128 tile, global_load_lds + XOR-swizzled LDS ----
__global__ __launch_bounds__(256, 2) void mgemm_kernel(const short* __restrict__ A,
                                                       const short* __restrict__ W,
                                                       short* __restrict__ C) {
    __shared__ __align__(16) short As[128 * 32];
    __shared__ __align__(16) short Ws[128 * 32];
    int tid = threadIdx.x;
    int lane = tid & 63, wv = tid >> 6, fr = lane & 15, fc = lane >> 4;
    int m0 = blockIdx.x * 128, n0 = blockIdx.y * 128;
    int srow = lane >> 2;                        // staging: row within 16-row chunk
    int scol = (lane & 3) ^ ((lane >> 3) & 3);   // staging: pre-swizzled 16B slot
    const short* gsrc[4];
    short* ldst[4];
#pragma unroll
    for (int i = 0; i < 4; ++i) {
        int ch = wv * 4 + i;
        if (ch < 8) {
            ldst[i] = &As[ch * 512];
            gsrc[i] = A + (size_t)(m0 + ch * 16 + srow) * FHC + scol * 8;
        } else {
            ldst[i] = &Ws[(ch - 8) * 512];
            gsrc[i] = W + (size_t)(n0 + (ch - 8) * 16 + srow) * FHC + scol * 8;
        }
    }
    int fcs = fc ^ ((fr >> 1) & 3);  // read-side swizzled slot
    facc acc[2][8] = {};
    for (int k0 = 0; k0 < FHC; k0 += 32) {
#pragma unroll
        for (int i = 0; i < 4; ++i) gld16(gsrc[i] + k0, ldst[i]);
        __syncthreads();
        int ar = (wv * 32 + fr) * 32 + fcs * 8;
        bfrag a0 = *reinterpret_cast<bfrag*>(&As[ar]);
        bfrag a1 = *reinterpret_cast<bfrag*>(&As[ar + 16 * 32]);
#pragma unroll
        for (int cf = 0; cf < 8; ++cf) {
            bfrag b = *reinterpret_cast<bfrag*>(&Ws[(cf * 16 + fr) * 32 + fcs * 8]);
            acc[0][cf] = __builtin_amdgcn_mfma_f32_16x16x32_bf16(a0, b, acc[0][cf], 0, 0, 0);
            acc[1][cf] = __builtin_amdgcn_mfma_f32_16x16x32_bf16(a1, b, acc[1][cf], 0, 0, 0);
        }
        __syncthreads();
    }
#pragma unroll
    for (int s = 0; s < 2; ++s)
#pragma unroll
        for (int cf = 0; cf < 8; ++cf)
#pragma unroll
            for (int r = 0; r < 4; ++r) {
                int node = m0 + wv * 32 + s * 16 + fc * 4 + r;
                int c = n0 + cf * 16 + fr;
                C[(size_t)node * FHC + c] = f2bf(acc[s][cf][r]);
            }
}

// ---------------- fused GRU: weight-stationary registers + streamed A tiles ----------------
// grid (128, 4); block = 4 waves, 2 blocks/CU (weight-stationary needs ~200 regs -> AGPRs;
// launch_bounds(256,4) forces spill, measured 1GB scratch traffic in R8). Per 16-row tile:
// stage agg+h (16KB, dbuf, gld16+swizzle), counted vmcnt(8), 48 barrier-free MFMA,
// LDS-hold + fast-math epilogue.
__global__ __launch_bounds__(256, 2) void gru_mfma_kernel(
    const short* __restrict__ agg16, const short* __restrict__ hin, short* __restrict__ hout,
    const short* __restrict__ wih16, const short* __restrict__ whh16,
    const float* __restrict__ bih, const float* __restrict__ bhh) {
    __shared__ __align__(16) short lds[2 * 16 * 512];  // 2 bufs x (8 agg + 8 h chunks) x 1KB
    int tid = threadIdx.x;
    int lane = tid & 63, wv = tid >> 6, fr = lane & 15, fc = lane >> 4;
    int c = blockIdx.y * 64 + wv * 16 + fr;  // gate column owned by this lane

    // ---- weight registers: 6 mats x 8 ksteps, static-indexed (VGPR/AGPR resident) ----
    bfrag wreg[6][8];
    {
        size_t roff = (size_t)c * FHC + fc * 8;
#pragma unroll
        for (int ks = 0; ks < 8; ++ks) {
            wreg[0][ks] = *reinterpret_cast<const bfrag*>(wih16 + roff + ks * 32);
            wreg[1][ks] = *reinterpret_cast<const bfrag*>(wih16 + (size_t)256 * FHC + roff + ks * 32);
            wreg[2][ks] = *reinterpret_cast<const bfrag*>(wih16 + (size_t)512 * FHC + roff + ks * 32);
            wreg[3][ks] = *reinterpret_cast<const bfrag*>(whh16 + roff + ks * 32);
            wreg[4][ks] = *reinterpret_cast<const bfrag*>(whh16 + (size_t)256 * FHC + roff + ks * 32);
            wreg[5][ks] = *reinterpret_cast<const bfrag*>(whh16 + (size_t)512 * FHC + roff + ks * 32);
        }
    }
    float br = bih[c] + bhh[c];
    float bz = bih[c + 256] + bhh[c + 256];
    float big = bih[c + 512], bhg = bhh[c + 512];

    // ---- staging setup: 16 chunks (8 agg + 8 h), 4 per wave ----
    int srow = lane >> 2;
    int scol = (lane & 3) ^ ((lane >> 3) & 3);
    const short* gb[4];
    int ldsoff[4];
#pragma unroll
    for (int i = 0; i < 4; ++i) {
        int ch = wv * 4 + i;
        int mat = ch >> 3, ks = ch & 7;
        const short* src = mat ? hin : agg16;
        gb[i] = src + (size_t)srow * FHC + ks * 32 + scol * 8;
        ldsoff[i] = ch * 512;
    }
    int fcs = fc ^ ((fr >> 1) & 3);
    int lo = (fr * 4 + fcs) * 8;
    const int NT = 32;
    int tile0 = blockIdx.x * NT;

    // hold = hin[node, c] read from the staged H tile in LDS (inverse write swizzle):
    // chunk 8+(c>>5); within: (row*4 + ((c>>3)&3 ^ ((row>>1)&3)))*8 + (c&7)
    int hbase = (8 + (c >> 5)) * 512 + (c & 7);
    int hg = (c >> 3) & 3;

    auto STAGE = [&](int t, int bufsel) {
        size_t noff = (size_t)(tile0 + t) * 16 * FHC;
        short* dst = &lds[bufsel * 8192];
#pragma unroll
        for (int i = 0; i < 4; ++i) gld16(gb[i] + noff, dst + ldsoff[i]);
    };

    STAGE(0, 0);
    for (int t = 0; t < NT; ++t) {
        int cur = t & 1;
        if (t + 1 < NT) {
            STAGE(t + 1, cur ^ 1);
            // in flight: stores epi(t-1)<=4 + stage(t+1)=4; vmcnt(8) drains stage(t)
            asm volatile("s_waitcnt vmcnt(8)" ::: "memory");
        } else {
            asm volatile("s_waitcnt vmcnt(0)" ::: "memory");
        }
        __builtin_amdgcn_sched_barrier(0);
        __builtin_amdgcn_s_barrier();
        const short* B = &lds[cur * 8192];
        facc aR = {}, aZ = {}, aG = {}, aH = {};
#pragma unroll
        for (int ks = 0; ks < 8; ++ks) {
            bfrag ag = *reinterpret_cast<const bfrag*>(B + ks * 512 + lo);
            bfrag hh = *reinterpret_cast<const bfrag*>(B + (8 + ks) * 512 + lo);
            aR = __builtin_amdgcn_mfma_f32_16x16x32_bf16(ag, wreg[0][ks], aR, 0, 0, 0);
            aR = __builtin_amdgcn_mfma_f32_16x16x32_bf16(hh, wreg[3][ks], aR, 0, 0, 0);
            aZ = __builtin_amdgcn_mfma_f32_16x16x32_bf16(ag, wreg[1][ks], aZ, 0, 0, 0);
            aZ = __builtin_amdgcn_mfma_f32_16x16x32_bf16(hh, wreg[4][ks], aZ, 0, 0, 0);
            aG = __builtin_amdgcn_mfma_f32_16x16x32_bf16(ag, wreg[2][ks], aG, 0, 0, 0);
            aH = __builtin_amdgcn_mfma_f32_16x16x32_bf16(hh, wreg[5][ks], aH, 0, 0, 0);
        }
        int node0 = (tile0 + t) * 16;
#pragma unroll
        for (int r = 0; r < 4; ++r) {
            int row = fc * 4 + r;
            float hold = bf2f(B[hbase + (row * 4 + (hg ^ ((row >> 1) & 3))) * 8]);
            float rg = fast_sigmoid(aR[r] + br);
            float z = fast_sigmoid(aZ[r] + bz);
            float g = fast_tanh(aG[r] + big + rg * (aH[r] + bhg));
            hout[(size_t)(node0 + row) * FHC + c] = f2bf(g + z * (hold - g));
        }
        __builtin_amdgcn_s_barrier();  // buf[cur] fully consumed before stage(t+2) overwrites
    }
}

// ---------------- conv1d(k=1) head: y1[n] = relu(sum_f relu(h[n,f])*w[f] + b) ----------------
__global__ void cnn_kernel(const short* __restrict__ h, const float* __restrict__ w,
                           const float* __restrict__ b, float* __restrict__ y1) {
    int node = blockIdx.x * 4 + (threadIdx.x >> 6);
    int lane = threadIdx.x & 63;
    short4 hv = reinterpret_cast<const short4*>(h)[(size_t)node * 64 + lane];
    float4 wv = reinterpret_cast<const float4*>(w)[lane];
    float p = fmaxf(bf2f(hv.x), 0.f) * wv.x + fmaxf(bf2f(hv.y), 0.f) * wv.y +
              fmaxf(bf2f(hv.z), 0.f) * wv.z + fmaxf(bf2f(hv.w), 0.f) * wv.w;
#pragma unroll
    for (int off = 32; off > 0; off >>= 1) p += __shfl_down(p, off, 64);
    if (lane == 0) y1[node] = fmaxf(p + b[0], 0.f);
}

// ---------------- per-graph MLP + softmax ----------------
__global__ __launch_bounds__(256) void head_kernel(
    const float* __restrict__ y1, const float* __restrict__ l1w,
    const float* __restrict__ l1b, const float* __restrict__ l2w,
    const float* __restrict__ l2b, float* __restrict__ out) {
    __shared__ float ys[32];
    __shared__ float zs[256];
    __shared__ float os[3];
    int b = blockIdx.x, tid = threadIdx.x;
    if (tid < 32) ys[tid] = y1[b * 32 + tid];
    __syncthreads();
    float acc = l1b[tid];
#pragma unroll
    for (int k = 0; k < 32; ++k) acc += ys[k] * l1w[tid * 32 + k];
    zs[tid] = fmaxf(acc, 0.f);
    __syncthreads();
    int wave = tid >> 6, lane = tid & 63;
    if (wave < 3) {
        float p = 0.f;
#pragma unroll
        for (int j = 0; j < 4; ++j) p += zs[lane + j * 64] * l2w[wave * 256 + lane + j * 64];
#pragma unroll
        for (int off = 32; off > 0; off >>= 1) p += __shfl_down(p, off, 64);
        if (lane == 0) os[wave] = p + l2b[wave];
    }
    __syncthreads();
    if (tid == 0) {
        float mx = fmaxf(os[0], fmaxf(os[1], os[2]));
        float e0 = expf(os[0] - mx), e1 = expf(os[1] - mx), e2 = expf(os[2] - mx);
        float s = e0 + e1 + e2;
        out[b * 3 + 0] = e0 / s;
        out[b * 3 + 1] = e1 / s;
        out[b * 3 + 2] = e2 / s;
    }
}

extern "C" void kernel_launch(void* const* d_in, const int* in_sizes, int n_in,
                              void* d_out, int out_size, void* d_ws, size_t ws_size,
                              hipStream_t stream) {
    const float* x = (const float*)d_in[0];
    const int* ei = (const int*)d_in[1];
    const float* ea = (const float*)d_in[2];
    const float* gg_w = (const float*)d_in[3];
    const float* w_ih = (const float*)d_in[4];
    const float* w_hh = (const float*)d_in[5];
    const float* b_ih = (const float*)d_in[6];
    const float* b_hh = (const float*)d_in[7];
    const float* cnn_w = (const float*)d_in[8];
    const float* cnn_b = (const float*)d_in[9];
    const float* l1w = (const float*)d_in[10];
    const float* l1b = (const float*)d_in[11];
    const float* l2w = (const float*)d_in[12];
    const float* l2b = (const float*)d_in[13];
    float* out = (float*)d_out;

    const size_t nodeE = (size_t)N_NODES * FHC;
    char* p = (char*)d_ws;
    short* hA = (short*)p;      p += nodeE * 2;
    short* hB = (short*)p;      p += nodeE * 2;
    short* m16 = (short*)p;     p += nodeE * 2;
    short* agg16 = (short*)p;   p += nodeE * 2;
    short* ggT = (short*)p;     p += (size_t)2 * FHC * FHC * 2;
    short* wih16 = (short*)p;   p += (size_t)3 * FHC * FHC * 2;
    short* whh16 = (short*)p;   p += (size_t)3 * FHC * FHC * 2;
    float* y1 = (float*)p;      p += (size_t)N_NODES * 4;
    int* deg = (int*)p;         p += (size_t)N_NODES * 4;
    int* rowptr = (int*)p;      p += (size_t)(N_NODES + 4) * 4;
    int* cur = (int*)p;         p += (size_t)N_NODES * 4;
    int* bsum = (int*)p;        p += 256 * 4;
    int* boff = (int*)p;        p += 256 * 4;
    int2* csr = (int2*)p;       p += (size_t)N_EDGES * 8;

    dim3 grid_gemm(N_NODES / 128, FHC / 128);
    dim3 grid_gru(128, 4);

    // weights + input prep
    convert_kernel<<<8 * FHC * FHC / 256, 256, 0, stream>>>(gg_w, w_ih, w_hh, ggT, wih16, whh16);
    pad16_kernel<<<N_NODES * 64 / 256, 256, 0, stream>>>(x, hA);

    // CSR build (per call; graph is a fixed input)
    hipMemsetAsync(deg, 0, (size_t)N_NODES * 4, stream);
    hist_kernel<<<N_EDGES / 256, 256, 0, stream>>>(ei, deg);
    scan_reduce_kernel<<<N_NODES / 256, 256, 0, stream>>>(deg, bsum);
    scan_bsum_kernel<<<1, 256, 0, stream>>>(bsum, boff);
    scan_write_kernel<<<N_NODES / 256, 256, 0, stream>>>(deg, boff, rowptr, cur);
    fill_kernel<<<N_EDGES / 256, 256, 0, stream>>>(ei, ea, cur, csr);

    // layer 0: hA -> m16 -> agg16 -> hB
    mgemm_kernel<<<grid_gemm, 256, 0, stream>>>(hA, ggT, m16);
    gather_kernel<<<N_NODES / 4, 256, 0, stream>>>(m16, rowptr, csr, agg16);
    gru_mfma_kernel<<<grid_gru, 256, 0, stream>>>(agg16, hA, hB, wih16, whh16, b_ih, b_hh);

    // layer 1: hB -> m16 -> agg16 -> hA
    mgemm_kernel<<<grid_gemm, 256, 0, stream>>>(hB, ggT + FHC * FHC, m16);
    gather_kernel<<<N_NODES / 4, 256, 0, stream>>>(m16, rowptr, csr, agg16);
    gru_mfma_kernel<<<grid_gru, 256, 0, stream>>>(agg16, hB, hA, wih16, whh16, b_ih, b_hh);

    cnn_kernel<<<N_NODES / 4, 256, 0, stream>>>(hA, cnn_w, cnn_b, y1);
    head_kernel<<<NGRAPH, 256, 0, stream>>>(y1, l1w, l1b, l2w, l2b, out);
}